// Round 7
// baseline (846.288 us; speedup 1.0000x reference)
//
#include <hip/hip_runtime.h>

#define N_NODES 100000
#define N_EDGES 1600000
#define D 64
#define NB 782            // buckets: src>>7, 128 nodes each (last: 32)
#define NBLK 391          // hist/scatter blocks: 4096 edges each
#define SCOUNT (NB * NBLK)   // 305,762
#define SCHUNKS 299          // ceil(SCOUNT/1024)

// ---- ws layout (4-byte units); all entries kernel-written, no memset ----
#define WS_COUNTS  0          // [SCOUNT]  counts[bin*NBLK + blk]
#define WS_OFFS    305792     // [SCOUNT]  exclusive scan of counts
#define WS_CSUM    611584     // [512]     chunk sums for scan
#define WS_PAIRS   612096     // int2[N_EDGES] (dst, val)   8B-aligned
#define WS_SLOCAL  3812096    // uchar[N_EDGES] src&127
// end: 4,212,096 ints = 16.8 MB <= proven ws >= 20.4 MB

// -------- pass 1: per-block bucket histogram (LDS, no global atomics) --------
__global__ __launch_bounds__(256) void k_bhist(
    const int* __restrict__ esrc, int* __restrict__ counts)
{
    __shared__ int h[NB];
    int t = threadIdx.x, blk = blockIdx.x;
    for (int i = t; i < NB; i += 256) h[i] = 0;
    __syncthreads();
    int base = blk * 4096 + t;
    #pragma unroll
    for (int i = 0; i < 16; ++i) {
        int e = base + i * 256;
        if (e < N_EDGES) atomicAdd(&h[esrc[e] >> 7], 1);
    }
    __syncthreads();
    for (int i = t; i < NB; i += 256)
        counts[i * NBLK + blk] = h[i];
}

// -------- 3-kernel exclusive scan over counts[SCOUNT] -> offs --------
__global__ __launch_bounds__(1024) void k_scan_local(
    const int* __restrict__ counts, int* __restrict__ offs, int* __restrict__ csum)
{
    __shared__ int wsum[16];
    int t = threadIdx.x, lane = t & 63, wid = t >> 6;
    int i = blockIdx.x * 1024 + t;
    int v = (i < SCOUNT) ? counts[i] : 0;
    int s = v;
    #pragma unroll
    for (int off = 1; off < 64; off <<= 1) {
        int y = __shfl_up(s, off, 64);
        if (lane >= off) s += y;
    }
    if (lane == 63) wsum[wid] = s;
    __syncthreads();
    if (t < 16) {
        int w = wsum[t];
        #pragma unroll
        for (int off = 1; off < 16; off <<= 1) {
            int y = __shfl_up(w, off, 16);
            if (t >= off) w += y;
        }
        wsum[t] = w;
    }
    __syncthreads();
    int prefix = wid ? wsum[wid - 1] : 0;
    if (i < SCOUNT) offs[i] = prefix + s - v;     // chunk-local exclusive
    if (t == 1023) csum[blockIdx.x] = prefix + s; // chunk total (wid=15 incl.)
}

__global__ __launch_bounds__(512) void k_scan_csum(int* __restrict__ csum)
{
    __shared__ int wsum[8];
    int t = threadIdx.x, lane = t & 63, wid = t >> 6;
    int v = (t < SCHUNKS) ? csum[t] : 0;
    int s = v;
    #pragma unroll
    for (int off = 1; off < 64; off <<= 1) {
        int y = __shfl_up(s, off, 64);
        if (lane >= off) s += y;
    }
    if (lane == 63) wsum[wid] = s;
    __syncthreads();
    if (t < 8) {
        int w = wsum[t];
        #pragma unroll
        for (int off = 1; off < 8; off <<= 1) {
            int y = __shfl_up(w, off, 8);
            if (t >= off) w += y;
        }
        wsum[t] = w;
    }
    __syncthreads();
    int prefix = wid ? wsum[wid - 1] : 0;
    if (t < SCHUNKS) csum[t] = prefix + s - v;    // exclusive chunk bases
}

__global__ __launch_bounds__(1024) void k_scan_add(
    int* __restrict__ offs, const int* __restrict__ csum)
{
    int i = blockIdx.x * 1024 + threadIdx.x;
    if (i < SCOUNT) offs[i] += csum[blockIdx.x];
}

// -------- pass 2: scatter edges into bucket segments (LDS cursors) --------
__global__ __launch_bounds__(1024) void k_bscatter(
    const int* __restrict__ esrc, const int* __restrict__ edst,
    const float* __restrict__ eval_, const int* __restrict__ offs,
    int2* __restrict__ pairs, unsigned char* __restrict__ slocal)
{
    __shared__ int cur[NB];
    int t = threadIdx.x, blk = blockIdx.x;
    for (int i = t; i < NB; i += 1024) cur[i] = offs[i * NBLK + blk];
    __syncthreads();
    int base = blk * 4096 + t;
    #pragma unroll
    for (int i = 0; i < 4; ++i) {
        int e = base + i * 1024;
        if (e < N_EDGES) {
            int s = esrc[e];
            int pos = atomicAdd(&cur[s >> 7], 1);
            pairs[pos] = make_int2(edst[e], __float_as_int(eval_[e]));
            slocal[pos] = (unsigned char)(s & 127);
        }
    }
}

// -------- fused aggregation: LDS accumulate + rep write --------
// One block per bucket (128 nodes, 32KB acc). 8 waves, 8-deep gather ILP
// (24 waves/CU x 8 in flight = same MLP as the proven R3/R6 gather).
__global__ __launch_bounds__(512) void k_baccum(
    const float* __restrict__ x, const int* __restrict__ offs,
    const int2* __restrict__ pairs, const unsigned char* __restrict__ slocal,
    const float* __restrict__ epsilon, float* __restrict__ rep)
{
    __shared__ float acc[128 * D];   // 32 KB
    int t = threadIdx.x, lane = t & 63, wave = t >> 6;
    int b = blockIdx.x;
    for (int i = t; i < 128 * D; i += 512) acc[i] = 0.0f;
    int start = offs[b * NBLK];
    int end = (b + 1 < NB) ? offs[(b + 1) * NBLK] : N_EDGES;
    __syncthreads();

    int cs = start + wave * 8;
    for (; cs + 8 <= end; cs += 64) {
        int2 p[8]; int sl[8]; float a[8];
        #pragma unroll
        for (int u = 0; u < 8; ++u) p[u] = pairs[cs + u];
        #pragma unroll
        for (int u = 0; u < 8; ++u) sl[u] = slocal[cs + u];
        #pragma unroll
        for (int u = 0; u < 8; ++u) a[u] = x[(size_t)p[u].x * D + lane];
        #pragma unroll
        for (int u = 0; u < 8; ++u)
            atomicAdd(&acc[sl[u] * D + lane], __int_as_float(p[u].y) * a[u]);
    }
    for (; cs < end; ++cs) {   // at most one partial chunk per wave
        int2 p = pairs[cs];
        int sl = slocal[cs];
        atomicAdd(&acc[sl * D + lane], __int_as_float(p.y) * x[(size_t)p.x * D + lane]);
    }
    __syncthreads();

    float eps = epsilon[0];
    int base_row = b * 128;
    int nrows = N_NODES - base_row; if (nrows > 128) nrows = 128;
    for (int r = wave; r < nrows; r += 8) {
        size_t g = (size_t)(base_row + r) * D + lane;
        rep[g] = acc[r * D + lane] + eps * x[g];
    }
}

// -------- out = rep @ W + bias (proven R3 kernel) --------
#define GEMM_TM 64
__global__ __launch_bounds__(256) void k_gemm(
    const float* __restrict__ rep, const float* __restrict__ weight,
    const float* __restrict__ bias, float* __restrict__ out)
{
    __shared__ float rep_s[GEMM_TM * 68];
    __shared__ float Ws[D * D];
    int t = threadIdx.x;
    {
        const float4* w4 = (const float4*)weight;
        float4* s4 = (float4*)Ws;
        #pragma unroll
        for (int i = 0; i < (D * D / 4) / 256; ++i)
            s4[t + i * 256] = w4[t + i * 256];
    }
    int row0 = blockIdx.x * GEMM_TM;
    {
        const float4* r4 = (const float4*)rep;
        #pragma unroll
        for (int i = 0; i < 4; ++i) {
            int f = t + i * 256;
            int rr = f >> 4, kk4 = f & 15;
            float4 v = (row0 + rr < N_NODES) ? r4[(size_t)(row0 + rr) * 16 + kk4]
                                             : make_float4(0.f, 0.f, 0.f, 0.f);
            rep_s[rr * 68 + kk4 * 4 + 0] = v.x;
            rep_s[rr * 68 + kk4 * 4 + 1] = v.y;
            rep_s[rr * 68 + kk4 * 4 + 2] = v.z;
            rep_s[rr * 68 + kk4 * 4 + 3] = v.w;
        }
    }
    __syncthreads();

    int tx = t & 15, ty = t >> 4;
    float4 b4 = ((const float4*)bias)[tx];
    float acc[4][4];
    #pragma unroll
    for (int i = 0; i < 4; ++i) {
        acc[i][0] = b4.x; acc[i][1] = b4.y; acc[i][2] = b4.z; acc[i][3] = b4.w;
    }
    #pragma unroll 4
    for (int k4 = 0; k4 < 16; ++k4) {
        float4 rv[4];
        #pragma unroll
        for (int i = 0; i < 4; ++i)
            rv[i] = *(const float4*)&rep_s[(ty * 4 + i) * 68 + k4 * 4];
        #pragma unroll
        for (int kk = 0; kk < 4; ++kk) {
            float4 wv = *(const float4*)&Ws[(k4 * 4 + kk) * D + tx * 4];
            #pragma unroll
            for (int i = 0; i < 4; ++i) {
                float r = ((const float*)&rv[i])[kk];
                acc[i][0] += r * wv.x;
                acc[i][1] += r * wv.y;
                acc[i][2] += r * wv.z;
                acc[i][3] += r * wv.w;
            }
        }
    }
    #pragma unroll
    for (int i = 0; i < 4; ++i) {
        int row = row0 + ty * 4 + i;
        if (row < N_NODES)
            *(float4*)&out[(size_t)row * D + tx * 4] =
                make_float4(acc[i][0], acc[i][1], acc[i][2], acc[i][3]);
    }
}

extern "C" void kernel_launch(void* const* d_in, const int* in_sizes, int n_in,
                              void* d_out, int out_size, void* d_ws, size_t ws_size,
                              hipStream_t stream) {
    const float* x    = (const float*)d_in[0];
    const int*   esrc = (const int*)  d_in[1];
    const int*   edst = (const int*)  d_in[2];
    const float* ev   = (const float*)d_in[3];
    const float* w    = (const float*)d_in[4];
    const float* eps  = (const float*)d_in[5];
    const float* bias = (const float*)d_in[6];

    float* out = (float*)d_out;
    float* rep = out + (size_t)N_NODES * D;

    int* ws = (int*)d_ws;
    int* counts = ws + WS_COUNTS;
    int* offs   = ws + WS_OFFS;
    int* csum   = ws + WS_CSUM;
    int2* pairs = (int2*)(ws + WS_PAIRS);
    unsigned char* slocal = (unsigned char*)(ws + WS_SLOCAL);

    k_bhist     <<<NBLK, 256, 0, stream>>>(esrc, counts);
    k_scan_local<<<SCHUNKS, 1024, 0, stream>>>(counts, offs, csum);
    k_scan_csum <<<1, 512, 0, stream>>>(csum);
    k_scan_add  <<<SCHUNKS, 1024, 0, stream>>>(offs, csum);
    k_bscatter  <<<NBLK, 1024, 0, stream>>>(esrc, edst, ev, offs, pairs, slocal);
    k_baccum    <<<NB, 512, 0, stream>>>(x, offs, pairs, slocal, eps, rep);
    k_gemm      <<<(N_NODES + GEMM_TM - 1) / GEMM_TM, 256, 0, stream>>>(rep, w, bias, out);
}